// Round 4
// baseline (501.207 us; speedup 1.0000x reference)
//
#include <hip/hip_runtime.h>

// ---------------------------------------------------------------------------
// Kernel 1: planar (2,H,W) f32 -> interleaved pre-scaled float2 image in ws.
//   im[y*W+x] = { dP[1][y][x] * 2/(H-1),  dP[0][y][x] * 2/(W-1) }
// Channel reversal (dP[::-1]) and (2/sizes) scaling folded in. Single
// rounding per element -> bitwise identical to scaling at sample time.
// ---------------------------------------------------------------------------
__global__ __launch_bounds__(256) void interleave_kernel(
    const float* __restrict__ dP, float2* __restrict__ im,
    int HW, float s0, float s1)
{
    int i = blockIdx.x * blockDim.x + threadIdx.x;   // quad-pixel index
    int nquad = HW >> 2;
    if (i >= nquad) return;
    const float4* p0 = reinterpret_cast<const float4*>(dP);        // dP[0]
    const float4* p1 = reinterpret_cast<const float4*>(dP + HW);   // dP[1]
    float4 a = p1[i];   // -> .x lane of im (scaled by s0)
    float4 b = p0[i];   // -> .y lane of im (scaled by s1)
    float4 lo, hi;
    lo.x = a.x * s0; lo.y = b.x * s1; lo.z = a.y * s0; lo.w = b.y * s1;
    hi.x = a.z * s0; hi.y = b.z * s1; hi.z = a.w * s0; hi.w = b.w * s1;
    float4* outv = reinterpret_cast<float4*>(im);
    outv[2 * i]     = lo;
    outv[2 * i + 1] = hi;
}

// ---------------------------------------------------------------------------
// Kernel 2: trajectory iteration, 2 points per thread (phase-split so all 8
// corner gathers are in flight before any use -> 2x memory-level parallelism
// vs 1 pt/thread; latency-bound regime).
//   USE_IM=true : gather from interleaved float2 image (1 float2 per corner)
//   USE_IM=false: gather planar dP, scale inline (bit-identical fallback if
//                 ws_size is too small for the 32 MB image)
// fp contract OFF: keep IEEE op-for-op parity with the reference formula —
// 60 dependent iterations are rounding-sensitive.
// ---------------------------------------------------------------------------
template <bool USE_IM>
__global__ __launch_bounds__(256) void iterate2_kernel(
    const float2* __restrict__ im, const float* __restrict__ dP,
    const int* __restrict__ inds, const int* __restrict__ niter_p,
    float* __restrict__ out, int H, int W, int N)
{
#pragma clang fp contract(off)
    const int t = blockIdx.x * blockDim.x + threadIdx.x;
    const int halfN = (N + 1) >> 1;
    if (t >= halfN) return;
    const int niter = niter_p[0];
    const float sH = (float)(H - 1);   // sizes[0]
    const float sW = (float)(W - 1);   // sizes[1]
    const float s0 = 2.0f / sH;        // scale for im ch0 (= dP[1])
    const float s1 = 2.0f / sW;        // scale for im ch1 (= dP[0])
    const int HW = H * W;
    const float Wf = (float)W, Hf = (float)H;

    int   pid[2];  pid[0] = t;  pid[1] = t + halfN;
    const bool act1 = (pid[1] < N);
    if (!act1) pid[1] = t;          // duplicate work, discard at the end

    float px[2], py[2];
#pragma unroll
    for (int k = 0; k < 2; ++k) {
        // pt0 = ([inds[1], inds[0]] / sizes) * 2 - 1   (reference op order)
        px[k] = ((float)inds[N + pid[k]] / sH) * 2.0f - 1.0f;
        py[k] = ((float)inds[pid[k]]     / sW) * 2.0f - 1.0f;
    }

    for (int it = 0; it < niter; ++it) {
        float wx1[2], wy1[2];
        bool  bx0[2], bx1[2], by0[2], by1[2];
        float2 v00[2], v10[2], v01[2], v11[2];

        // ---- phase 1: addresses + issue all 8 gathers --------------------
#pragma unroll
        for (int k = 0; k < 2; ++k) {
            float x = ((px[k] + 1.0f) * Wf - 1.0f) * 0.5f;
            float y = ((py[k] + 1.0f) * Hf - 1.0f) * 0.5f;
            float x0f = floorf(x), y0f = floorf(y);
            wx1[k] = x - x0f;  wy1[k] = y - y0f;
            int x0 = (int)x0f, y0 = (int)y0f;
            int x1 = x0 + 1,   y1 = y0 + 1;
            int x0c = min(max(x0, 0), W - 1);
            int x1c = min(max(x1, 0), W - 1);
            int y0c = min(max(y0, 0), H - 1);
            int y1c = min(max(y1, 0), H - 1);
            bx0[k] = (x0 >= 0) & (x0 < W);
            bx1[k] = (x1 >= 0) & (x1 < W);
            by0[k] = (y0 >= 0) & (y0 < H);
            by1[k] = (y1 >= 0) & (y1 < H);
            if (USE_IM) {
                const float2* r0 = im + (size_t)y0c * W;
                const float2* r1 = im + (size_t)y1c * W;
                v00[k] = r0[x0c]; v10[k] = r0[x1c];
                v01[k] = r1[x0c]; v11[k] = r1[x1c];
            } else {
                int i00 = y0c * W + x0c, i10 = y0c * W + x1c;
                int i01 = y1c * W + x0c, i11 = y1c * W + x1c;
                v00[k] = make_float2(dP[HW + i00] * s0, dP[i00] * s1);
                v10[k] = make_float2(dP[HW + i10] * s0, dP[i10] * s1);
                v01[k] = make_float2(dP[HW + i01] * s0, dP[i01] * s1);
                v11[k] = make_float2(dP[HW + i11] * s0, dP[i11] * s1);
            }
        }

        // ---- phase 2: mask, weight, accumulate, clip ---------------------
#pragma unroll
        for (int k = 0; k < 2; ++k) {
            const float2 zero = make_float2(0.0f, 0.0f);
            if (!(bx0[k] & by0[k])) v00[k] = zero;
            if (!(bx1[k] & by0[k])) v10[k] = zero;
            if (!(bx0[k] & by1[k])) v01[k] = zero;
            if (!(bx1[k] & by1[k])) v11[k] = zero;
            float wx0 = 1.0f - wx1[k], wy0 = 1.0f - wy1[k];
            float w00 = wx0 * wy0,   w10 = wx1[k] * wy0;
            float w01 = wx0 * wy1[k], w11 = wx1[k] * wy1[k];
            // left-to-right sum, exactly as the reference
            float dx = ((v00[k].x * w00 + v10[k].x * w10) + v01[k].x * w01) + v11[k].x * w11;
            float dy = ((v00[k].y * w00 + v10[k].y * w10) + v01[k].y * w01) + v11[k].y * w11;
            px[k] = fminf(fmaxf(px[k] + dx, -1.0f), 1.0f);
            py[k] = fminf(fmaxf(py[k] + dy, -1.0f), 1.0f);
        }
    }

    // pt = (pt+1)*0.5*sizes; output rows swapped: row0 <- pt[:,1], row1 <- pt[:,0]
    out[pid[0]]     = (py[0] + 1.0f) * 0.5f * sW;
    out[N + pid[0]] = (px[0] + 1.0f) * 0.5f * sH;
    if (act1) {
        out[pid[1]]     = (py[1] + 1.0f) * 0.5f * sW;
        out[N + pid[1]] = (px[1] + 1.0f) * 0.5f * sH;
    }
}

extern "C" void kernel_launch(void* const* d_in, const int* in_sizes, int n_in,
                              void* d_out, int out_size, void* d_ws, size_t ws_size,
                              hipStream_t stream) {
    const float* dP      = (const float*)d_in[0];
    const int*   inds    = (const int*)d_in[1];
    const int*   niter_p = (const int*)d_in[2];
    float*       out     = (float*)d_out;

    const int HW = in_sizes[0] / 2;
    int W = 1;
    while ((long long)W * W < (long long)HW) W <<= 1;  // 4194304 -> 2048
    const int H = HW / W;
    const int N = in_sizes[1] / 2;
    const int halfN = (N + 1) >> 1;

    const float s0 = 2.0f / (float)(H - 1);
    const float s1 = 2.0f / (float)(W - 1);

    const size_t im_bytes = (size_t)HW * sizeof(float2);
    if (ws_size >= im_bytes) {
        float2* im = (float2*)d_ws;
        const int nquad = HW / 4;
        interleave_kernel<<<(nquad + 255) / 256, 256, 0, stream>>>(
            dP, im, HW, s0, s1);
        iterate2_kernel<true><<<(halfN + 255) / 256, 256, 0, stream>>>(
            im, dP, inds, niter_p, out, H, W, N);
    } else {
        iterate2_kernel<false><<<(halfN + 255) / 256, 256, 0, stream>>>(
            nullptr, dP, inds, niter_p, out, H, W, N);
    }
}

// Round 9
// 274.674 us; speedup vs baseline: 1.8247x; 1.8247x over previous
//
#include <hip/hip_runtime.h>

#define TILE_SHIFT 5   // 32x32-pixel tiles: ~8KB/tile, 4096 tiles at 2048^2

// ---------------------------------------------------------------------------
// Kernel 1: planar (2,H,W) f32 -> interleaved pre-scaled float2 image in ws.
//   im[y*W+x] = { dP[1][y][x] * 2/(H-1),  dP[0][y][x] * 2/(W-1) }
// Single rounding per element -> bitwise identical to scaling at sample time.
// ---------------------------------------------------------------------------
__global__ __launch_bounds__(256) void interleave_kernel(
    const float* __restrict__ dP, float2* __restrict__ im,
    int HW, float s0, float s1)
{
    int i = blockIdx.x * blockDim.x + threadIdx.x;   // quad-pixel index
    int nquad = HW >> 2;
    if (i >= nquad) return;
    const float4* p0 = reinterpret_cast<const float4*>(dP);        // dP[0]
    const float4* p1 = reinterpret_cast<const float4*>(dP + HW);   // dP[1]
    float4 a = p1[i];
    float4 b = p0[i];
    float4 lo, hi;
    lo.x = a.x * s0; lo.y = b.x * s1; lo.z = a.y * s0; lo.w = b.y * s1;
    hi.x = a.z * s0; hi.y = b.z * s1; hi.z = a.w * s0; hi.w = b.w * s1;
    float4* outv = reinterpret_cast<float4*>(im);
    outv[2 * i]     = lo;
    outv[2 * i + 1] = hi;
}

// ---------------------------------------------------------------------------
// Spatial binning: points drift only ~8px over 60 iters, so initial position
// is a good locality key. hist -> exclusive scan -> scatter builds perm[]
// such that consecutive slots hold points from the same 32x32 tile.
// ---------------------------------------------------------------------------
__global__ __launch_bounds__(256) void zero_kernel(int* __restrict__ p, int n)
{
    int i = blockIdx.x * blockDim.x + threadIdx.x;
    if (i < n) p[i] = 0;
}

__device__ __forceinline__ int point_tile(const int* inds, int n, int N,
                                          int H, int W, int tiles_x)
{
    int y = inds[n];        // row index (0..H-1)
    int x = inds[N + n];    // col index (0..W-1)
    int ty = min(max(y, 0), H - 1) >> TILE_SHIFT;
    int tx = min(max(x, 0), W - 1) >> TILE_SHIFT;
    return ty * tiles_x + tx;
}

__global__ __launch_bounds__(256) void hist_kernel(
    const int* __restrict__ inds, int* __restrict__ hist,
    int N, int H, int W, int tiles_x)
{
    int n = blockIdx.x * blockDim.x + threadIdx.x;
    if (n >= N) return;
    atomicAdd(&hist[point_tile(inds, n, N, H, W, tiles_x)], 1);
}

// single block, 1024 threads: exclusive scan of hist -> cursor
__global__ __launch_bounds__(1024) void scan_kernel(
    const int* __restrict__ hist, int* __restrict__ cursor, int ntiles)
{
    __shared__ int partial[1024];
    const int tid = threadIdx.x;
    const int items = (ntiles + 1023) >> 10;
    const int base = tid * items;
    int sum = 0;
    for (int i = 0; i < items; ++i) {
        int idx = base + i;
        if (idx < ntiles) sum += hist[idx];
    }
    partial[tid] = sum;
    __syncthreads();
    for (int off = 1; off < 1024; off <<= 1) {
        int v = (tid >= off) ? partial[tid - off] : 0;
        __syncthreads();
        partial[tid] += v;
        __syncthreads();
    }
    int excl = (tid == 0) ? 0 : partial[tid - 1];
    for (int i = 0; i < items; ++i) {
        int idx = base + i;
        if (idx < ntiles) {
            int h = hist[idx];
            cursor[idx] = excl;
            excl += h;
        }
    }
}

__global__ __launch_bounds__(256) void scatter_kernel(
    const int* __restrict__ inds, int* __restrict__ cursor,
    int* __restrict__ perm, int N, int H, int W, int tiles_x)
{
    int n = blockIdx.x * blockDim.x + threadIdx.x;
    if (n >= N) return;
    int slot = atomicAdd(&cursor[point_tile(inds, n, N, H, W, tiles_x)], 1);
    perm[slot] = n;
}

// ---------------------------------------------------------------------------
// Trajectory iteration, 2 points per thread, phase-split (8 gathers in
// flight per iteration).  MODE 2: interleaved image + tile-sorted perm
// (consecutive slots -> same tile -> L1/L2-resident working set).
// MODE 1: interleaved image, unsorted (round-4 verified behavior).
// MODE 0: planar dP fallback (tiny ws).
// fp contract OFF: IEEE op-for-op parity with the reference formula.
// ---------------------------------------------------------------------------
template <int MODE>
__global__ __launch_bounds__(256) void iterate2_kernel(
    const float2* __restrict__ im, const float* __restrict__ dP,
    const int* __restrict__ perm,
    const int* __restrict__ inds, const int* __restrict__ niter_p,
    float* __restrict__ out, int H, int W, int N)
{
#pragma clang fp contract(off)
    const int t = blockIdx.x * blockDim.x + threadIdx.x;
    const int halfN = (N + 1) >> 1;
    if (t >= halfN) return;
    const int niter = niter_p[0];
    const float sH = (float)(H - 1);   // sizes[0]
    const float sW = (float)(W - 1);   // sizes[1]
    const float s0 = 2.0f / sH;
    const float s1 = 2.0f / sW;
    const int HW = H * W;
    const float Wf = (float)W, Hf = (float)H;

    int pid[2];
    bool act1;
    if (MODE == 2) {
        // consecutive sorted slots -> same spatial tile
        int i0 = 2 * t, i1 = 2 * t + 1;
        act1 = (i1 < N);
        if (!act1) i1 = i0;
        pid[0] = perm[i0];
        pid[1] = perm[i1];
    } else {
        pid[0] = t;
        pid[1] = t + halfN;
        act1 = (pid[1] < N);
        if (!act1) pid[1] = t;
    }

    float px[2], py[2];
#pragma unroll
    for (int k = 0; k < 2; ++k) {
        // pt0 = ([inds[1], inds[0]] / sizes) * 2 - 1   (reference op order)
        px[k] = ((float)inds[N + pid[k]] / sH) * 2.0f - 1.0f;
        py[k] = ((float)inds[pid[k]]     / sW) * 2.0f - 1.0f;
    }

    for (int it = 0; it < niter; ++it) {
        float wx1[2], wy1[2];
        bool  bx0[2], bx1[2], by0[2], by1[2];
        float2 v00[2], v10[2], v01[2], v11[2];

        // ---- phase 1: addresses + issue all 8 gathers --------------------
#pragma unroll
        for (int k = 0; k < 2; ++k) {
            float x = ((px[k] + 1.0f) * Wf - 1.0f) * 0.5f;
            float y = ((py[k] + 1.0f) * Hf - 1.0f) * 0.5f;
            float x0f = floorf(x), y0f = floorf(y);
            wx1[k] = x - x0f;  wy1[k] = y - y0f;
            int x0 = (int)x0f, y0 = (int)y0f;
            int x1 = x0 + 1,   y1 = y0 + 1;
            int x0c = min(max(x0, 0), W - 1);
            int x1c = min(max(x1, 0), W - 1);
            int y0c = min(max(y0, 0), H - 1);
            int y1c = min(max(y1, 0), H - 1);
            bx0[k] = (x0 >= 0) & (x0 < W);
            bx1[k] = (x1 >= 0) & (x1 < W);
            by0[k] = (y0 >= 0) & (y0 < H);
            by1[k] = (y1 >= 0) & (y1 < H);
            if (MODE >= 1) {
                const float2* r0 = im + (size_t)y0c * W;
                const float2* r1 = im + (size_t)y1c * W;
                v00[k] = r0[x0c]; v10[k] = r0[x1c];
                v01[k] = r1[x0c]; v11[k] = r1[x1c];
            } else {
                int i00 = y0c * W + x0c, i10 = y0c * W + x1c;
                int i01 = y1c * W + x0c, i11 = y1c * W + x1c;
                v00[k] = make_float2(dP[HW + i00] * s0, dP[i00] * s1);
                v10[k] = make_float2(dP[HW + i10] * s0, dP[i10] * s1);
                v01[k] = make_float2(dP[HW + i01] * s0, dP[i01] * s1);
                v11[k] = make_float2(dP[HW + i11] * s0, dP[i11] * s1);
            }
        }

        // ---- phase 2: mask, weight, accumulate, clip ---------------------
#pragma unroll
        for (int k = 0; k < 2; ++k) {
            const float2 zero = make_float2(0.0f, 0.0f);
            if (!(bx0[k] & by0[k])) v00[k] = zero;
            if (!(bx1[k] & by0[k])) v10[k] = zero;
            if (!(bx0[k] & by1[k])) v01[k] = zero;
            if (!(bx1[k] & by1[k])) v11[k] = zero;
            float wx0 = 1.0f - wx1[k], wy0 = 1.0f - wy1[k];
            float w00 = wx0 * wy0,    w10 = wx1[k] * wy0;
            float w01 = wx0 * wy1[k], w11 = wx1[k] * wy1[k];
            // left-to-right sum, exactly as the reference
            float dx = ((v00[k].x * w00 + v10[k].x * w10) + v01[k].x * w01) + v11[k].x * w11;
            float dy = ((v00[k].y * w00 + v10[k].y * w10) + v01[k].y * w01) + v11[k].y * w11;
            px[k] = fminf(fmaxf(px[k] + dx, -1.0f), 1.0f);
            py[k] = fminf(fmaxf(py[k] + dy, -1.0f), 1.0f);
        }
    }

    // pt = (pt+1)*0.5*sizes; row0 <- pt[:,1], row1 <- pt[:,0]
    out[pid[0]]     = (py[0] + 1.0f) * 0.5f * sW;
    out[N + pid[0]] = (px[0] + 1.0f) * 0.5f * sH;
    if (act1) {
        out[pid[1]]     = (py[1] + 1.0f) * 0.5f * sW;
        out[N + pid[1]] = (px[1] + 1.0f) * 0.5f * sH;
    }
}

extern "C" void kernel_launch(void* const* d_in, const int* in_sizes, int n_in,
                              void* d_out, int out_size, void* d_ws, size_t ws_size,
                              hipStream_t stream) {
    const float* dP      = (const float*)d_in[0];
    const int*   inds    = (const int*)d_in[1];
    const int*   niter_p = (const int*)d_in[2];
    float*       out     = (float*)d_out;

    const int HW = in_sizes[0] / 2;
    int W = 1;
    while ((long long)W * W < (long long)HW) W <<= 1;  // 4194304 -> 2048
    const int H = HW / W;
    const int N = in_sizes[1] / 2;
    const int halfN = (N + 1) >> 1;

    const float s0 = 2.0f / (float)(H - 1);
    const float s1 = 2.0f / (float)(W - 1);

    const int tiles_x = ((W - 1) >> TILE_SHIFT) + 1;
    const int tiles_y = ((H - 1) >> TILE_SHIFT) + 1;
    const int ntiles  = tiles_x * tiles_y;

    const size_t im_bytes   = (size_t)HW * sizeof(float2);
    const size_t perm_bytes = (size_t)N * sizeof(int);
    const size_t aux_bytes  = (size_t)2 * ntiles * sizeof(int);  // hist + cursor

    char* base = (char*)d_ws;
    float2* im     = (float2*)base;
    int*    perm   = (int*)(base + im_bytes);
    int*    hist   = (int*)(base + im_bytes + perm_bytes);
    int*    cursor = hist + ntiles;

    const int nblkN = (N + 255) / 256;

    if (ws_size >= im_bytes + perm_bytes + aux_bytes) {
        // full path: interleave + tile-sort + sorted iterate
        interleave_kernel<<<(HW / 4 + 255) / 256, 256, 0, stream>>>(
            dP, im, HW, s0, s1);
        zero_kernel<<<(ntiles + 255) / 256, 256, 0, stream>>>(hist, ntiles);
        hist_kernel<<<nblkN, 256, 0, stream>>>(inds, hist, N, H, W, tiles_x);
        scan_kernel<<<1, 1024, 0, stream>>>(hist, cursor, ntiles);
        scatter_kernel<<<nblkN, 256, 0, stream>>>(inds, cursor, perm, N, H, W, tiles_x);
        iterate2_kernel<2><<<(halfN + 255) / 256, 256, 0, stream>>>(
            im, dP, perm, inds, niter_p, out, H, W, N);
    } else if (ws_size >= im_bytes) {
        interleave_kernel<<<(HW / 4 + 255) / 256, 256, 0, stream>>>(
            dP, im, HW, s0, s1);
        iterate2_kernel<1><<<(halfN + 255) / 256, 256, 0, stream>>>(
            im, dP, nullptr, inds, niter_p, out, H, W, N);
    } else {
        iterate2_kernel<0><<<(halfN + 255) / 256, 256, 0, stream>>>(
            nullptr, dP, nullptr, inds, niter_p, out, H, W, N);
    }
}

// Round 11
// 231.277 us; speedup vs baseline: 2.1671x; 1.1876x over previous
//
#include <hip/hip_runtime.h>

#define TILE_SHIFT 5   // 32x32-pixel tiles: 8KB/tile, 4096 tiles at 2048^2
#define NXCD 8

// ---------------------------------------------------------------------------
// Kernel 1: planar (2,H,W) f32 -> interleaved pre-scaled float2 image in ws.
//   im[y*W+x] = { dP[1][y][x] * 2/(H-1),  dP[0][y][x] * 2/(W-1) }
// XCD-swizzled: XCD k (bid%8) writes y-band k (rows [k*H/8,(k+1)*H/8)) so the
// iterate kernel's chunk k finds its band dirty-resident in its own L2.
// ---------------------------------------------------------------------------
__global__ __launch_bounds__(256) void interleave_kernel(
    const float* __restrict__ dP, float2* __restrict__ im,
    int HW, float s0, float s1, int swz_on)
{
    int bid = blockIdx.x;
    if (swz_on) {
        int cpx = gridDim.x >> 3;              // blocks per XCD chunk
        bid = (bid & (NXCD - 1)) * cpx + (bid >> 3);
    }
    int i = bid * blockDim.x + threadIdx.x;    // quad-pixel index
    int nquad = HW >> 2;
    if (i >= nquad) return;
    const float4* p0 = reinterpret_cast<const float4*>(dP);        // dP[0]
    const float4* p1 = reinterpret_cast<const float4*>(dP + HW);   // dP[1]
    float4 a = p1[i];
    float4 b = p0[i];
    float4 lo, hi;
    lo.x = a.x * s0; lo.y = b.x * s1; lo.z = a.y * s0; lo.w = b.y * s1;
    hi.x = a.z * s0; hi.y = b.z * s1; hi.z = a.w * s0; hi.w = b.w * s1;
    float4* outv = reinterpret_cast<float4*>(im);
    outv[2 * i]     = lo;
    outv[2 * i + 1] = hi;
}

// ---------------------------------------------------------------------------
// Spatial binning (unchanged, verified R9): hist -> scan -> scatter builds
// perm[] so consecutive slots hold points from the same 32x32 tile.
// ---------------------------------------------------------------------------
__global__ __launch_bounds__(256) void zero_kernel(int* __restrict__ p, int n)
{
    int i = blockIdx.x * blockDim.x + threadIdx.x;
    if (i < n) p[i] = 0;
}

__device__ __forceinline__ int point_tile(const int* inds, int n, int N,
                                          int H, int W, int tiles_x)
{
    int y = inds[n];        // row index
    int x = inds[N + n];    // col index
    int ty = min(max(y, 0), H - 1) >> TILE_SHIFT;
    int tx = min(max(x, 0), W - 1) >> TILE_SHIFT;
    return ty * tiles_x + tx;
}

__global__ __launch_bounds__(256) void hist_kernel(
    const int* __restrict__ inds, int* __restrict__ hist,
    int N, int H, int W, int tiles_x)
{
    int n = blockIdx.x * blockDim.x + threadIdx.x;
    if (n >= N) return;
    atomicAdd(&hist[point_tile(inds, n, N, H, W, tiles_x)], 1);
}

__global__ __launch_bounds__(1024) void scan_kernel(
    const int* __restrict__ hist, int* __restrict__ cursor, int ntiles)
{
    __shared__ int partial[1024];
    const int tid = threadIdx.x;
    const int items = (ntiles + 1023) >> 10;
    const int base = tid * items;
    int sum = 0;
    for (int i = 0; i < items; ++i) {
        int idx = base + i;
        if (idx < ntiles) sum += hist[idx];
    }
    partial[tid] = sum;
    __syncthreads();
    for (int off = 1; off < 1024; off <<= 1) {
        int v = (tid >= off) ? partial[tid - off] : 0;
        __syncthreads();
        partial[tid] += v;
        __syncthreads();
    }
    int excl = (tid == 0) ? 0 : partial[tid - 1];
    for (int i = 0; i < items; ++i) {
        int idx = base + i;
        if (idx < ntiles) {
            int h = hist[idx];
            cursor[idx] = excl;
            excl += h;
        }
    }
}

__global__ __launch_bounds__(256) void scatter_kernel(
    const int* __restrict__ inds, int* __restrict__ cursor,
    int* __restrict__ perm, int N, int H, int W, int tiles_x)
{
    int n = blockIdx.x * blockDim.x + threadIdx.x;
    if (n >= N) return;
    int slot = atomicAdd(&cursor[point_tile(inds, n, N, H, W, tiles_x)], 1);
    perm[slot] = n;
}

// ---------------------------------------------------------------------------
// Trajectory iteration, 1 point per thread (2x waves/CU vs R9's 2-pt variant;
// same aggregate MLP: 16 waves x 4 loads = 8 x 8).  XCD-swizzled so chunk k
// runs on XCD k, whose L2 holds y-band k written by interleave.
//   MODE 2: interleaved image + tile-sorted perm.  MODE 1: image, unsorted.
//   MODE 0: planar dP fallback.
// fp contract OFF: IEEE op-for-op parity with the reference formula.
// ---------------------------------------------------------------------------
template <int MODE>
__global__ __launch_bounds__(256) void iterate1_kernel(
    const float2* __restrict__ im, const float* __restrict__ dP,
    const int* __restrict__ perm,
    const int* __restrict__ inds, const int* __restrict__ niter_p,
    float* __restrict__ out, int H, int W, int N, int swz_on)
{
#pragma clang fp contract(off)
    int bid = blockIdx.x;
    if (swz_on) {
        int cpx = gridDim.x >> 3;
        bid = (bid & (NXCD - 1)) * cpx + (bid >> 3);
    }
    const int t = bid * blockDim.x + threadIdx.x;
    if (t >= N) return;
    const int niter = niter_p[0];
    const float sH = (float)(H - 1);   // sizes[0]
    const float sW = (float)(W - 1);   // sizes[1]
    const float s0 = 2.0f / sH;        // scale for im ch0 (= dP[1])
    const float s1 = 2.0f / sW;        // scale for im ch1 (= dP[0])
    const int HW = H * W;
    const float Wf = (float)W, Hf = (float)H;

    const int pid = (MODE == 2) ? perm[t] : t;

    // pt0 = ([inds[1], inds[0]] / sizes) * 2 - 1   (reference op order)
    float px = ((float)inds[N + pid] / sH) * 2.0f - 1.0f;
    float py = ((float)inds[pid]     / sW) * 2.0f - 1.0f;

    for (int it = 0; it < niter; ++it) {
        float x = ((px + 1.0f) * Wf - 1.0f) * 0.5f;
        float y = ((py + 1.0f) * Hf - 1.0f) * 0.5f;
        float x0f = floorf(x), y0f = floorf(y);
        float wx1 = x - x0f,  wy1 = y - y0f;
        float wx0 = 1.0f - wx1, wy0 = 1.0f - wy1;
        int x0 = (int)x0f, y0 = (int)y0f;
        int x1 = x0 + 1,   y1 = y0 + 1;

        int x0c = min(max(x0, 0), W - 1);
        int x1c = min(max(x1, 0), W - 1);
        int y0c = min(max(y0, 0), H - 1);
        int y1c = min(max(y1, 0), H - 1);
        bool bx0 = (x0 >= 0) & (x0 < W);
        bool bx1 = (x1 >= 0) & (x1 < W);
        bool by0 = (y0 >= 0) & (y0 < H);
        bool by1 = (y1 >= 0) & (y1 < H);

        float2 v00, v10, v01, v11;
        if (MODE >= 1) {
            const float2* r0 = im + (size_t)y0c * W;
            const float2* r1 = im + (size_t)y1c * W;
            v00 = r0[x0c]; v10 = r0[x1c];
            v01 = r1[x0c]; v11 = r1[x1c];
        } else {
            int i00 = y0c * W + x0c, i10 = y0c * W + x1c;
            int i01 = y1c * W + x0c, i11 = y1c * W + x1c;
            v00 = make_float2(dP[HW + i00] * s0, dP[i00] * s1);
            v10 = make_float2(dP[HW + i10] * s0, dP[i10] * s1);
            v01 = make_float2(dP[HW + i01] * s0, dP[i01] * s1);
            v11 = make_float2(dP[HW + i11] * s0, dP[i11] * s1);
        }
        const float2 zero = make_float2(0.0f, 0.0f);
        if (!(bx0 & by0)) v00 = zero;
        if (!(bx1 & by0)) v10 = zero;
        if (!(bx0 & by1)) v01 = zero;
        if (!(bx1 & by1)) v11 = zero;

        float w00 = wx0 * wy0, w10 = wx1 * wy0;
        float w01 = wx0 * wy1, w11 = wx1 * wy1;
        // left-to-right sum, exactly as the reference
        float dx = ((v00.x * w00 + v10.x * w10) + v01.x * w01) + v11.x * w11;
        float dy = ((v00.y * w00 + v10.y * w10) + v01.y * w01) + v11.y * w11;

        px = fminf(fmaxf(px + dx, -1.0f), 1.0f);
        py = fminf(fmaxf(py + dy, -1.0f), 1.0f);
    }

    // pt = (pt+1)*0.5*sizes; row0 <- pt[:,1], row1 <- pt[:,0]
    out[pid]     = (py + 1.0f) * 0.5f * sW;
    out[N + pid] = (px + 1.0f) * 0.5f * sH;
}

extern "C" void kernel_launch(void* const* d_in, const int* in_sizes, int n_in,
                              void* d_out, int out_size, void* d_ws, size_t ws_size,
                              hipStream_t stream) {
    const float* dP      = (const float*)d_in[0];
    const int*   inds    = (const int*)d_in[1];
    const int*   niter_p = (const int*)d_in[2];
    float*       out     = (float*)d_out;

    const int HW = in_sizes[0] / 2;
    int W = 1;
    while ((long long)W * W < (long long)HW) W <<= 1;  // 4194304 -> 2048
    const int H = HW / W;
    const int N = in_sizes[1] / 2;

    const float s0 = 2.0f / (float)(H - 1);
    const float s1 = 2.0f / (float)(W - 1);

    const int tiles_x = ((W - 1) >> TILE_SHIFT) + 1;
    const int tiles_y = ((H - 1) >> TILE_SHIFT) + 1;
    const int ntiles  = tiles_x * tiles_y;

    const size_t im_bytes   = (size_t)HW * sizeof(float2);
    const size_t perm_bytes = (size_t)N * sizeof(int);
    const size_t aux_bytes  = (size_t)2 * ntiles * sizeof(int);  // hist + cursor

    char* base = (char*)d_ws;
    float2* im     = (float2*)base;
    int*    perm   = (int*)(base + im_bytes);
    int*    hist   = (int*)(base + im_bytes + perm_bytes);
    int*    cursor = hist + ntiles;

    const int nblkN  = (N + 255) / 256;
    const int nblkIm = (HW / 4 + 255) / 256;
    const int swzIm  = (nblkIm % NXCD) == 0 && (HW / 4) % 256 == 0;
    const int swzIt  = (nblkN % NXCD) == 0 && (N % 256) == 0;

    if (ws_size >= im_bytes + perm_bytes + aux_bytes) {
        // full path: XCD-banded interleave + tile-sort + XCD-banded iterate
        interleave_kernel<<<nblkIm, 256, 0, stream>>>(
            dP, im, HW, s0, s1, swzIm);
        zero_kernel<<<(ntiles + 255) / 256, 256, 0, stream>>>(hist, ntiles);
        hist_kernel<<<nblkN, 256, 0, stream>>>(inds, hist, N, H, W, tiles_x);
        scan_kernel<<<1, 1024, 0, stream>>>(hist, cursor, ntiles);
        scatter_kernel<<<nblkN, 256, 0, stream>>>(inds, cursor, perm, N, H, W, tiles_x);
        iterate1_kernel<2><<<nblkN, 256, 0, stream>>>(
            im, dP, perm, inds, niter_p, out, H, W, N, swzIt);
    } else if (ws_size >= im_bytes) {
        interleave_kernel<<<nblkIm, 256, 0, stream>>>(
            dP, im, HW, s0, s1, swzIm);
        iterate1_kernel<1><<<nblkN, 256, 0, stream>>>(
            im, dP, nullptr, inds, niter_p, out, H, W, N, 0);
    } else {
        iterate1_kernel<0><<<nblkN, 256, 0, stream>>>(
            nullptr, dP, nullptr, inds, niter_p, out, H, W, N, 0);
    }
}